// Round 3
// baseline (40.504 us; speedup 1.0000x reference)
//
#include <hip/hip_runtime.h>

// Problem constants (from reference): B=32, C=4, L=512
constexpr int B = 32;
constexpr int C = 4;
constexpr int L = 512;
constexpr int THREADS = 256;   // 4 waves
constexpr int RPB = 8;         // rows per block -> 2 rows per wave

// Unaligned-tolerant 16B load (ligand side is only dword-aligned).
__device__ inline float4 ld4u(const float* p) {
    float4 v;
    __builtin_memcpy(&v, p, sizeof(float4));
    return v;
}

// out[b*C+c] = sum_{x,y valid} receptor[b,c,x,y] * ligand[b,c,x-dx,y-dy]
// Window sizes are >= 256 in both dims (|dx|,|dy| <= 256), so the quad count
// per row nq is in [64,128]: quad q=lane is ALWAYS valid, q=64+lane valid iff
// lane < nq-64. This lets the whole row be two predicated quad-pairs with no
// control flow -> all loads issue before any vmcnt wait (max MLP).
__global__ __launch_bounds__(THREADS)
void imgmul_kernel(const float* __restrict__ receptor,
                   const float* __restrict__ ligand,
                   const int* __restrict__ T,
                   float* __restrict__ out)
{
    const int bc = blockIdx.x;           // 0..B*C-1
    const int b  = bc >> 2;              // C == 4
    const int dx = T[2 * b + 0];
    const int dy = T[2 * b + 1];

    const int x0 = dx > 0 ? dx : 0;
    const int x1 = (L + dx) < L ? (L + dx) : L;
    const int y0 = dy > 0 ? dy : 0;
    const int y1 = (L + dy) < L ? (L + dy) : L;

    const int ya    = (y0 + 3) & ~3;     // receptor-aligned quad base
    const int head  = ya - y0;           // 0..3
    const int nq    = (y1 - ya) >> 2;    // 64..128
    const int rem   = (y1 - ya) & 3;     // 0..3
    const int ytail = ya + 4 * nq;
    const int nq2   = nq - 64;           // 0..64

    const size_t plane = (size_t)bc * (L * L);
    const float* rec = receptor + plane;
    const float* lig = ligand + plane;

    const int wave = threadIdx.x >> 6;
    const int lane = threadIdx.x & 63;
    const int rbase = blockIdx.y * RPB;

    // Per-lane column coordinates (shared by both rows). All clamped so every
    // load address is in-bounds; invalid lanes masked out at combine time.
    const int  yq0 = ya + 4 * lane;                    // always valid
    const bool v1  = lane < nq2;
    const int  yq1 = v1 ? (ya + 4 * (64 + lane)) : ya;
    const bool vh  = lane < head;
    const int  yh  = vh ? (y0 + lane) : y0;
    const bool vt  = lane < rem;
    const int  yt  = vt ? (ytail + lane) : y0;

    // Row coordinates for this wave (2 rows, stride 4).
    const int xA = rbase + wave;
    const int xB = rbase + wave + 4;
    const bool vA = (xA >= x0) & (xA < x1);
    const bool vB = (xB >= x0) & (xB < x1);
    const int xcA = vA ? xA : x0;
    const int xcB = vB ? xB : x0;

    const float* rrowA = rec + (size_t)xcA * L;
    const float* lrowA = lig + (size_t)(xcA - dx) * L - dy;
    const float* rrowB = rec + (size_t)xcB * L;
    const float* lrowB = lig + (size_t)(xcB - dx) * L - dy;

    // ---- Phase A: issue ALL loads (single basic block, no branches) ----
    const float4 rA0 = *reinterpret_cast<const float4*>(rrowA + yq0);
    const float4 lA0 = ld4u(lrowA + yq0);
    const float4 rA1 = *reinterpret_cast<const float4*>(rrowA + yq1);
    const float4 lA1 = ld4u(lrowA + yq1);
    const float4 rB0 = *reinterpret_cast<const float4*>(rrowB + yq0);
    const float4 lB0 = ld4u(lrowB + yq0);
    const float4 rB1 = *reinterpret_cast<const float4*>(rrowB + yq1);
    const float4 lB1 = ld4u(lrowB + yq1);
    const float rhA = rrowA[yh], lhA = lrowA[yh];
    const float rtA = rrowA[yt], ltA = lrowA[yt];
    const float rhB = rrowB[yh], lhB = lrowB[yh];
    const float rtB = rrowB[yt], ltB = lrowB[yt];

    // ---- Phase B: arithmetic, masked combines ----
    float dA0 = rA0.x * lA0.x;
    dA0 = fmaf(rA0.y, lA0.y, dA0);
    dA0 = fmaf(rA0.z, lA0.z, dA0);
    dA0 = fmaf(rA0.w, lA0.w, dA0);
    float dA1 = rA1.x * lA1.x;
    dA1 = fmaf(rA1.y, lA1.y, dA1);
    dA1 = fmaf(rA1.z, lA1.z, dA1);
    dA1 = fmaf(rA1.w, lA1.w, dA1);
    float dB0 = rB0.x * lB0.x;
    dB0 = fmaf(rB0.y, lB0.y, dB0);
    dB0 = fmaf(rB0.z, lB0.z, dB0);
    dB0 = fmaf(rB0.w, lB0.w, dB0);
    float dB1 = rB1.x * lB1.x;
    dB1 = fmaf(rB1.y, lB1.y, dB1);
    dB1 = fmaf(rB1.z, lB1.z, dB1);
    dB1 = fmaf(rB1.w, lB1.w, dB1);

    float rowA = dA0 + (v1 ? dA1 : 0.0f);
    rowA += vh ? rhA * lhA : 0.0f;
    rowA += vt ? rtA * ltA : 0.0f;
    float rowB = dB0 + (v1 ? dB1 : 0.0f);
    rowB += vh ? rhB * lhB : 0.0f;
    rowB += vt ? rtB * ltB : 0.0f;

    float acc = (vA ? rowA : 0.0f) + (vB ? rowB : 0.0f);

    // ---- Wave reduce (64 lanes) ----
    #pragma unroll
    for (int off = 32; off > 0; off >>= 1)
        acc += __shfl_down(acc, off, 64);

    __shared__ float wsum[THREADS / 64];
    if (lane == 0) wsum[wave] = acc;
    __syncthreads();

    if (threadIdx.x == 0) {
        float s = wsum[0] + wsum[1] + wsum[2] + wsum[3];
        atomicAdd(&out[bc], s);
    }
}

extern "C" void kernel_launch(void* const* d_in, const int* in_sizes, int n_in,
                              void* d_out, int out_size, void* d_ws, size_t ws_size,
                              hipStream_t stream)
{
    const float* receptor = (const float*)d_in[0];
    const float* ligand   = (const float*)d_in[1];
    const int*   T        = (const int*)d_in[2];
    float* out = (float*)d_out;

    // Atomic accumulation target: zero it every launch (graph-safe memset node).
    hipMemsetAsync(d_out, 0, (size_t)out_size * sizeof(float), stream);

    dim3 grid(B * C, L / RPB);
    imgmul_kernel<<<grid, dim3(THREADS), 0, stream>>>(receptor, ligand, T, out);
}

// Round 4
// 32.356 us; speedup vs baseline: 1.2518x; 1.2518x over previous
//
#include <hip/hip_runtime.h>

// Problem constants (from reference): B=32, C=4, L=512
constexpr int B = 32;
constexpr int C = 4;
constexpr int L = 512;
constexpr int THREADS = 256;   // 4 waves
constexpr int RPB = 8;         // rows per block -> 2 rows per wave
constexpr int CHUNKS = L / RPB; // 64 row-chunks per plane

// Unaligned-tolerant 16B load (ligand side is only dword-aligned).
__device__ inline float4 ld4u(const float* p) {
    float4 v;
    __builtin_memcpy(&v, p, sizeof(float4));
    return v;
}

// Stage 1: one block per (row-chunk, plane). blockIdx.x = chunk (FASTEST) so
// concurrently-resident blocks read a contiguous few-plane region -> near-
// sequential chip-wide DRAM order (the m13-copy pattern), instead of 8192
// scattered row-streams spanning all 256 MB.
__global__ __launch_bounds__(THREADS)
void imgmul_stage1(const float* __restrict__ receptor,
                   const float* __restrict__ ligand,
                   const int* __restrict__ T,
                   float* __restrict__ partials)
{
    const int chunk = blockIdx.x;        // 0..CHUNKS-1
    const int bc    = blockIdx.y;        // 0..B*C-1
    const int b     = bc >> 2;           // C == 4
    const int dx = T[2 * b + 0];
    const int dy = T[2 * b + 1];

    const int x0 = dx > 0 ? dx : 0;
    const int x1 = (L + dx) < L ? (L + dx) : L;
    const int y0 = dy > 0 ? dy : 0;
    const int y1 = (L + dy) < L ? (L + dy) : L;

    const int ya    = (y0 + 3) & ~3;     // receptor-aligned quad base
    const int head  = ya - y0;           // 0..3
    const int nq    = (y1 - ya) >> 2;    // 64..128 (|dy| <= 256)
    const int rem   = (y1 - ya) & 3;     // 0..3
    const int ytail = ya + 4 * nq;
    const int nq2   = nq - 64;           // 0..64

    const size_t plane = (size_t)bc * (L * L);
    const float* rec = receptor + plane;
    const float* lig = ligand + plane;

    const int wave = threadIdx.x >> 6;
    const int lane = threadIdx.x & 63;
    const int rbase = chunk * RPB;

    // Per-lane column coordinates; invalid lanes clamp addresses in-bounds and
    // are masked at combine time (single basic block -> max loads in flight).
    const int  yq0 = ya + 4 * lane;                    // always valid
    const bool v1  = lane < nq2;
    const int  yq1 = v1 ? (ya + 4 * (64 + lane)) : ya;
    const bool vh  = lane < head;
    const int  yh  = vh ? (y0 + lane) : y0;
    const bool vt  = lane < rem;
    const int  yt  = vt ? (ytail + lane) : y0;

    const int xA = rbase + wave;
    const int xB = rbase + wave + 4;
    const bool vA = (xA >= x0) & (xA < x1);
    const bool vB = (xB >= x0) & (xB < x1);
    const int xcA = vA ? xA : x0;
    const int xcB = vB ? xB : x0;

    const float* rrowA = rec + (size_t)xcA * L;
    const float* lrowA = lig + (size_t)(xcA - dx) * L - dy;
    const float* rrowB = rec + (size_t)xcB * L;
    const float* lrowB = lig + (size_t)(xcB - dx) * L - dy;

    // ---- Issue all loads ----
    const float4 rA0 = *reinterpret_cast<const float4*>(rrowA + yq0);
    const float4 lA0 = ld4u(lrowA + yq0);
    const float4 rA1 = *reinterpret_cast<const float4*>(rrowA + yq1);
    const float4 lA1 = ld4u(lrowA + yq1);
    const float4 rB0 = *reinterpret_cast<const float4*>(rrowB + yq0);
    const float4 lB0 = ld4u(lrowB + yq0);
    const float4 rB1 = *reinterpret_cast<const float4*>(rrowB + yq1);
    const float4 lB1 = ld4u(lrowB + yq1);
    const float rhA = rrowA[yh], lhA = lrowA[yh];
    const float rtA = rrowA[yt], ltA = lrowA[yt];
    const float rhB = rrowB[yh], lhB = lrowB[yh];
    const float rtB = rrowB[yt], ltB = lrowB[yt];

    // ---- Arithmetic + masked combine ----
    float dA0 = rA0.x * lA0.x;
    dA0 = fmaf(rA0.y, lA0.y, dA0);
    dA0 = fmaf(rA0.z, lA0.z, dA0);
    dA0 = fmaf(rA0.w, lA0.w, dA0);
    float dA1 = rA1.x * lA1.x;
    dA1 = fmaf(rA1.y, lA1.y, dA1);
    dA1 = fmaf(rA1.z, lA1.z, dA1);
    dA1 = fmaf(rA1.w, lA1.w, dA1);
    float dB0 = rB0.x * lB0.x;
    dB0 = fmaf(rB0.y, lB0.y, dB0);
    dB0 = fmaf(rB0.z, lB0.z, dB0);
    dB0 = fmaf(rB0.w, lB0.w, dB0);
    float dB1 = rB1.x * lB1.x;
    dB1 = fmaf(rB1.y, lB1.y, dB1);
    dB1 = fmaf(rB1.z, lB1.z, dB1);
    dB1 = fmaf(rB1.w, lB1.w, dB1);

    float rowA = dA0 + (v1 ? dA1 : 0.0f);
    rowA += vh ? rhA * lhA : 0.0f;
    rowA += vt ? rtA * ltA : 0.0f;
    float rowB = dB0 + (v1 ? dB1 : 0.0f);
    rowB += vh ? rhB * lhB : 0.0f;
    rowB += vt ? rtB * ltB : 0.0f;

    float acc = (vA ? rowA : 0.0f) + (vB ? rowB : 0.0f);

    // ---- Wave reduce, then cross-wave via LDS ----
    #pragma unroll
    for (int off = 32; off > 0; off >>= 1)
        acc += __shfl_down(acc, off, 64);

    __shared__ float wsum[THREADS / 64];
    if (lane == 0) wsum[wave] = acc;
    __syncthreads();

    if (threadIdx.x == 0)
        partials[bc * CHUNKS + chunk] = wsum[0] + wsum[1] + wsum[2] + wsum[3];
}

// Stage 2: out[bc] = sum of its 64 partials (one wave per output).
__global__ __launch_bounds__(64)
void imgmul_stage2(const float* __restrict__ partials, float* __restrict__ out)
{
    const int bc = blockIdx.x;
    const int lane = threadIdx.x & 63;
    float v = partials[bc * CHUNKS + lane];
    #pragma unroll
    for (int off = 32; off > 0; off >>= 1)
        v += __shfl_down(v, off, 64);
    if (lane == 0) out[bc] = v;
}

extern "C" void kernel_launch(void* const* d_in, const int* in_sizes, int n_in,
                              void* d_out, int out_size, void* d_ws, size_t ws_size,
                              hipStream_t stream)
{
    const float* receptor = (const float*)d_in[0];
    const float* ligand   = (const float*)d_in[1];
    const int*   T        = (const int*)d_in[2];
    float* out      = (float*)d_out;
    float* partials = (float*)d_ws;      // 8192 floats = 32 KB of scratch

    // Stage 1 fully writes all B*C*CHUNKS partials; stage 2 fully writes out.
    // No memset / no atomics needed (deterministic, poison-safe).
    imgmul_stage1<<<dim3(CHUNKS, B * C), dim3(THREADS), 0, stream>>>(
        receptor, ligand, T, partials);
    imgmul_stage2<<<dim3(B * C), dim3(64), 0, stream>>>(partials, out);
}